// Round 25
// baseline (289.852 us; speedup 1.0000x reference)
//
#include <hip/hip_runtime.h>

#define N_NODES 50000
#define N_EDGES 800000
#define IN_F 96
#define H_F 256
#define N_NIE 4
#define SCAN_NB 196   // ceil(50000/256)
#define BM 64         // mega rows per block
#define NBLK 782      // ceil(50000/64)
#define LDA1 104      // A-lds stride (shorts): 208B rows
// merged count+prep kernel grid partition
#define CP_COUNT_NB 1563                   // ceil(400000/256) int2 edge pairs
#define PREP_NORM_NB 12500                 // 4 nodes/block (wave per node)
#define PREP_WS_NB 384                     // ceil(4*96*256/256)
#define PREP_WF_NB 1024                    // ceil(4*256*256/256)

typedef float f32x4 __attribute__((ext_vector_type(4)));
typedef short s16x8 __attribute__((ext_vector_type(8)));
typedef unsigned short ushort;

__device__ __forceinline__ ushort bf16_rne(float f) {
    unsigned u = __float_as_uint(f);
    u += 0x7fffu + ((u >> 16) & 1u);
    return (ushort)(u >> 16);
}
__device__ __forceinline__ float bf16_f(ushort h) {
    return __uint_as_float(((unsigned)h) << 16);
}

// ---------------- merged: edge-degree count + row-normalize + weight re-layouts ----------------
__global__ __launch_bounds__(256) void k_count_prep(const int* __restrict__ rows,
                                                    const int* __restrict__ cols,
                                                    int* __restrict__ cnt,
                                                    const float* __restrict__ feat,
                                                    ushort* __restrict__ x,
                                                    const float* __restrict__ Ws,
                                                    ushort* __restrict__ Ws2,
                                                    const float* __restrict__ Wf,
                                                    ushort* __restrict__ Wf2) {
    int blk = blockIdx.x;
    if (blk < CP_COUNT_NB) {
        int i = blk * 256 + threadIdx.x;
        if (i >= N_EDGES / 2) return;
        int2 r2 = ((const int2*)rows)[i];
        int2 c2 = ((const int2*)cols)[i];
        if (r2.x != c2.x) atomicAdd(&cnt[r2.x], 1);
        if (r2.y != c2.y) atomicAdd(&cnt[r2.y], 1);
    } else if (blk < CP_COUNT_NB + PREP_NORM_NB) {
        int wid = ((blk - CP_COUNT_NB) * 256 + threadIdx.x) >> 6;
        int lane = threadIdx.x & 63;
        if (wid >= N_NODES) return;
        const float* fr = feat + (size_t)wid * IN_F;
        float v0 = (lane < IN_F) ? fr[lane] : 0.0f;
        float v1 = (lane < IN_F - 64) ? fr[64 + lane] : 0.0f;
        float ss = v0 * v0 + v1 * v1;
        #pragma unroll
        for (int o = 32; o; o >>= 1) ss += __shfl_xor(ss, o, 64);
        float inv = 1.0f / fmaxf(sqrtf(ss), 1e-12f);
        ushort* xr = x + (size_t)wid * IN_F;
        if (lane < IN_F) xr[lane] = bf16_rne(v0 * inv);
        if (lane < IN_F - 64) xr[64 + lane] = bf16_rne(v1 * inv);
    } else if (blk < CP_COUNT_NB + PREP_NORM_NB + PREP_WS_NB) {
        int idx = (blk - CP_COUNT_NB - PREP_NORM_NB) * 256 + threadIdx.x;
        if (idx >= N_NIE * IN_F * H_F) return;
        int hop = idx / (IN_F * H_F), rem = idx % (IN_F * H_F);
        int k = rem / H_F, n = rem % H_F;
        int c = n >> 6, wc = (n >> 5) & 1, b = (n >> 4) & 1, rsel = n & 15;
        int ks = k >> 5, kk = k & 31;
        int lane = (kk >> 3) * 16 + rsel, sel8 = kk & 7;
        int d = (((((hop * 4 + c) * 2 + wc) * 2 + b) * 3 + ks) * 64 + lane) * 8 + sel8;
        Ws2[d] = bf16_rne(Ws[idx]);
    } else {
        int idx = (blk - CP_COUNT_NB - PREP_NORM_NB - PREP_WS_NB) * 256 + threadIdx.x;
        if (idx >= N_NIE * H_F * H_F) return;
        int hop = idx / (H_F * H_F), rem = idx % (H_F * H_F);
        int k = rem / H_F, n = rem % H_F;
        int kc = k >> 5, kk = k & 31;
        int w = n >> 5, rem2 = n & 31;
        int cf = rem2 >> 4, rsel = rem2 & 15;
        int lane = (kk >> 3) * 16 + rsel, sel8 = kk & 7;
        int d = ((((hop * 8 + kc) * 8 + w) * 2 + cf) * 64 + lane) * 8 + sel8;
        Wf2[d] = bf16_rne(Wf[idx]);
    }
}

__global__ __launch_bounds__(256) void k_scan1(const int* __restrict__ cnt,
                                               int* __restrict__ rowptr,
                                               int* __restrict__ bsum) {
    __shared__ int s[256];
    int t = threadIdx.x, e = blockIdx.x * 256 + t;
    int v = (e < N_NODES) ? cnt[e] : 0;
    s[t] = v;
    __syncthreads();
    #pragma unroll
    for (int off = 1; off < 256; off <<= 1) {
        int nv = (t >= off) ? s[t - off] : 0;
        __syncthreads();
        s[t] += nv;
        __syncthreads();
    }
    if (e < N_NODES) rowptr[e] = s[t] - v;
    if (t == 255) bsum[blockIdx.x] = s[255];
}

__global__ __launch_bounds__(256) void k_scan2(int* __restrict__ bsum,
                                               int* __restrict__ boff,
                                               int* __restrict__ rowptr) {
    __shared__ int s[256];
    int t = threadIdx.x;
    int v = (t < SCAN_NB) ? bsum[t] : 0;
    s[t] = v;
    __syncthreads();
    #pragma unroll
    for (int off = 1; off < 256; off <<= 1) {
        int nv = (t >= off) ? s[t - off] : 0;
        __syncthreads();
        s[t] += nv;
        __syncthreads();
    }
    if (t < SCAN_NB) boff[t] = s[t] - v;
    if (t == 255) rowptr[N_NODES] = s[255];
}

__global__ __launch_bounds__(256) void k_scan3(const int* __restrict__ boff,
                                               const int* __restrict__ cnt,
                                               int* __restrict__ rowptr,
                                               int* __restrict__ cursor,
                                               float* __restrict__ dinv) {
    int e = blockIdx.x * 256 + threadIdx.x;
    if (e >= N_NODES) return;
    int r = rowptr[e] + boff[blockIdx.x];
    rowptr[e] = r;
    cursor[e] = r;
    dinv[e] = rsqrtf((float)cnt[e] + 1.0f);
}

// single-pass scatter; packs (col, dinv[col])
__global__ __launch_bounds__(256) void k_scatter(const int* __restrict__ rows,
                                                 const int* __restrict__ cols,
                                                 const float* __restrict__ dinv,
                                                 int* __restrict__ cursor,
                                                 int2* __restrict__ cw) {
    int e = blockIdx.x * 256 + threadIdx.x;
    if (e >= N_EDGES) return;
    int r = rows[e], c = cols[e];
    if (r == c) return;  // set_diag zeroes pre-existing diagonal entries
    int p = atomicAdd(&cursor[r], 1);
    long long v = ((long long)(unsigned)__float_as_int(dinv[c]) << 32) | (unsigned)c;
    __builtin_nontemporal_store(v, (long long*)&cw[p]);
}

// ---------------- CSR SpMM: 16-lane group/row, packed (c,w) int2, s16x8 gathers, unroll 8 ----
__global__ __launch_bounds__(256) void k_spmm_csr(const int* __restrict__ rowptr,
                                                  const int2* __restrict__ cw,
                                                  const float* __restrict__ dinv,
                                                  const ushort* __restrict__ x,
                                                  ushort* __restrict__ y) {
    int g = (blockIdx.x * 256 + threadIdx.x) >> 4;
    if (g >= N_NODES) return;
    int l = threadIdx.x & 15;
    bool act = l < 12;
    float dr = dinv[g];
    s16x8 sv = {0, 0, 0, 0, 0, 0, 0, 0};
    if (act) sv = *(const s16x8*)&x[(size_t)g * IN_F + l * 8];
    float a[8] = {}, b[8] = {};
    int k = rowptr[g], e = rowptr[g + 1];
    for (; k + 7 < e; k += 8) {  // 8 gather chains in flight
        int2 p0 = cw[k],     p1 = cw[k + 1], p2 = cw[k + 2], p3 = cw[k + 3];
        int2 p4 = cw[k + 4], p5 = cw[k + 5], p6 = cw[k + 6], p7 = cw[k + 7];
        float w0 = __int_as_float(p0.y), w1 = __int_as_float(p1.y);
        float w2 = __int_as_float(p2.y), w3 = __int_as_float(p3.y);
        float w4 = __int_as_float(p4.y), w5 = __int_as_float(p5.y);
        float w6 = __int_as_float(p6.y), w7 = __int_as_float(p7.y);
        s16x8 v0 = {0, 0, 0, 0, 0, 0, 0, 0}, v1 = v0, v2 = v0, v3 = v0;
        s16x8 v4 = v0, v5 = v0, v6 = v0, v7 = v0;
        if (act) {
            v0 = *(const s16x8*)&x[(size_t)p0.x * IN_F + l * 8];
            v1 = *(const s16x8*)&x[(size_t)p1.x * IN_F + l * 8];
            v2 = *(const s16x8*)&x[(size_t)p2.x * IN_F + l * 8];
            v3 = *(const s16x8*)&x[(size_t)p3.x * IN_F + l * 8];
            v4 = *(const s16x8*)&x[(size_t)p4.x * IN_F + l * 8];
            v5 = *(const s16x8*)&x[(size_t)p5.x * IN_F + l * 8];
            v6 = *(const s16x8*)&x[(size_t)p6.x * IN_F + l * 8];
            v7 = *(const s16x8*)&x[(size_t)p7.x * IN_F + l * 8];
        }
        #pragma unroll
        for (int q = 0; q < 8; ++q) {
            a[q] += (bf16_f((ushort)v0[q]) * w0 + bf16_f((ushort)v1[q]) * w1) +
                    (bf16_f((ushort)v4[q]) * w4 + bf16_f((ushort)v5[q]) * w5);
            b[q] += (bf16_f((ushort)v2[q]) * w2 + bf16_f((ushort)v3[q]) * w3) +
                    (bf16_f((ushort)v6[q]) * w6 + bf16_f((ushort)v7[q]) * w7);
        }
    }
    for (; k + 1 < e; k += 2) {
        int2 p0 = cw[k], p1 = cw[k + 1];
        float w0 = __int_as_float(p0.y), w1 = __int_as_float(p1.y);
        s16x8 v0 = {0, 0, 0, 0, 0, 0, 0, 0}, v1 = v0;
        if (act) {
            v0 = *(const s16x8*)&x[(size_t)p0.x * IN_F + l * 8];
            v1 = *(const s16x8*)&x[(size_t)p1.x * IN_F + l * 8];
        }
        #pragma unroll
        for (int q = 0; q < 8; ++q)
            a[q] += bf16_f((ushort)v0[q]) * w0 + bf16_f((ushort)v1[q]) * w1;
    }
    if (k < e) {
        int2 p0 = cw[k];
        float w0 = __int_as_float(p0.y);
        s16x8 v0 = {0, 0, 0, 0, 0, 0, 0, 0};
        if (act) v0 = *(const s16x8*)&x[(size_t)p0.x * IN_F + l * 8];
        #pragma unroll
        for (int q = 0; q < 8; ++q) a[q] += bf16_f((ushort)v0[q]) * w0;
    }
    if (act) {
        s16x8 o;
        #pragma unroll
        for (int q = 0; q < 8; ++q)
            o[q] = (short)bf16_rne(dr * ((a[q] + b[q]) + dr * bf16_f((ushort)sv[q])));
        *(s16x8*)&y[(size_t)g * IN_F + l * 8] = o;
    }
}

// ---------------- MEGA v10 (unchanged, proven 102 us): frag-major weights, A-prefetch ----------------
__global__ __launch_bounds__(512, 4) void k_mega(const ushort* __restrict__ h0,
                                                 const ushort* __restrict__ h1,
                                                 const ushort* __restrict__ h2,
                                                 const ushort* __restrict__ h3,
                                                 const ushort* __restrict__ Ws2,
                                                 const float* __restrict__ bs,
                                                 const ushort* __restrict__ Wf2,
                                                 const float* __restrict__ bf,
                                                 float* __restrict__ out) {
    __shared__ ushort SM[23040];        // 46.1 KB
    ushort* nsH = SM;                   // [64][256] swizzled (16384)
    ushort* Ah  = SM + 16384;           // [64][LDA1] (6656)
    float* T = (float*)SM;              // epilogue scratch [32][260] f32 (aliases)

    int m0 = blockIdx.x * BM;
    int tid = threadIdx.x;
    int lane = tid & 63, w = tid >> 6;
    int rsel = lane & 15, g = lane >> 4, ksel = g * 8;
    int crow = g * 4, ccol = rsel;
    int rw0 = (w & 3) * 16;   // phase-1 row-fragment base
    int wc = w >> 2;          // phase-1 col-half (0/1)
    int cwb = wc * 32;

    int sr0 = tid / 12, sj0 = tid - sr0 * 12;  // A-stage item 0 of [64][12]
    int f1 = tid + 512;
    int sr1 = f1 / 12, sj1 = f1 - sr1 * 12;    // A-stage item 1 (tid < 256)
    int gm0 = m0 + sr0, gm1 = m0 + sr1;

    f32x4 acc[4][2] = {};  // persistent: rows rf*16.., cols w*32+cf*16..

    // ---- prologue: stage h0 into Ah ----
    {
        s16x8 v = {0, 0, 0, 0, 0, 0, 0, 0};
        if (gm0 < N_NODES) v = *(const s16x8*)&h0[(size_t)gm0 * IN_F + sj0 * 8];
        *(s16x8*)&Ah[sr0 * LDA1 + sj0 * 8] = v;
        if (tid < 256) {
            s16x8 v1 = {0, 0, 0, 0, 0, 0, 0, 0};
            if (gm1 < N_NODES) v1 = *(const s16x8*)&h0[(size_t)gm1 * IN_F + sj1 * 8];
            *(s16x8*)&Ah[sr1 * LDA1 + sj1 * 8] = v1;
        }
    }
    __syncthreads();

    for (int hop = 0; hop < N_NIE; ++hop) {
        const ushort* wsF = Ws2 + (size_t)hop * IN_F * H_F;  // frag-major
        const ushort* wfF = Wf2 + (size_t)hop * H_F * H_F;   // frag-major
        const float* bsi = bs + hop * H_F;

        // ---- phase 1: nsH = relu(A @ WsT + bs); B frags direct global ----
        #pragma unroll
        for (int c = 0; c < 4; ++c) {
            const ushort* bsrc = wsF + (size_t)((c * 2 + wc) * 2) * 3 * 64 * 8;  // b=0 base
            f32x4 ac[2] = {};
            #pragma unroll
            for (int ks = 0; ks < 3; ++ks) {
                s16x8 ah = *(const s16x8*)&Ah[(rw0 + rsel) * LDA1 + ks * 32 + ksel];
                s16x8 b0 = *(const s16x8*)&bsrc[(size_t)(ks * 64 + lane) * 8];
                s16x8 b1 = *(const s16x8*)&bsrc[(size_t)((3 + ks) * 64 + lane) * 8];
                ac[0] = __builtin_amdgcn_mfma_f32_16x16x32_bf16(ah, b0, ac[0], 0, 0, 0);
                ac[1] = __builtin_amdgcn_mfma_f32_16x16x32_bf16(ah, b1, ac[1], 0, 0, 0);
            }
            #pragma unroll
            for (int cf = 0; cf < 2; ++cf) {
                int col = c * 64 + cwb + cf * 16 + ccol;
                float bb = bsi[col];
                #pragma unroll
                for (int ii = 0; ii < 4; ++ii) {
                    int row = rw0 + crow + ii;
                    nsH[row * 256 + (col ^ ((row & 7) << 3))] =
                        bf16_rne(fmaxf(ac[cf][ii] + bb, 0.f));
                }
            }
        }
        __syncthreads();  // nsH complete; Ah reads drained -> Ah writable
        // ---- issue next-hop A loads (hidden under phase 2), write to Ah ----
        if (hop < N_NIE - 1) {
            const ushort* An = (hop == 0) ? h1 : (hop == 1) ? h2 : h3;
            s16x8 pv0 = {0, 0, 0, 0, 0, 0, 0, 0}, pv1 = pv0;
            if (gm0 < N_NODES) pv0 = *(const s16x8*)&An[(size_t)gm0 * IN_F + sj0 * 8];
            if (tid < 256 && gm1 < N_NODES) pv1 = *(const s16x8*)&An[(size_t)gm1 * IN_F + sj1 * 8];
            *(s16x8*)&Ah[sr0 * LDA1 + sj0 * 8] = pv0;
            if (tid < 256) *(s16x8*)&Ah[sr1 * LDA1 + sj1 * 8] = pv1;
        }
        // ---- phase 2: acc += ns @ WfT; W frags direct global ----
        #pragma unroll
        for (int kc = 0; kc < 8; ++kc) {
            int k0 = kc * 32 + ksel;
            s16x8 ah4[4];
            #pragma unroll
            for (int rf = 0; rf < 4; ++rf) {
                int row = rf * 16 + rsel;
                ah4[rf] = *(const s16x8*)&nsH[row * 256 + (k0 ^ ((row & 7) << 3))];
            }
            #pragma unroll
            for (int cf = 0; cf < 2; ++cf) {
                s16x8 bh = *(const s16x8*)&wfF[(size_t)(((kc * 8 + w) * 2 + cf) * 64 + lane) * 8];
                #pragma unroll
                for (int rf = 0; rf < 4; ++rf)
                    acc[rf][cf] = __builtin_amdgcn_mfma_f32_16x16x32_bf16(ah4[rf], bh, acc[rf][cf], 0, 0, 0);
            }
        }
        __syncthreads();  // nsH consumed + Ah(next) published
    }
    // ---- epilogue: transpose acc through LDS -> full-line float4 row stores ----
    #pragma unroll
    for (int half = 0; half < 2; ++half) {
        __syncthreads();  // prior T / LDS reads done
        #pragma unroll
        for (int rf2 = 0; rf2 < 2; ++rf2) {
            int rf = half * 2 + rf2;
            #pragma unroll
            for (int cf = 0; cf < 2; ++cf) {
                int col = w * 32 + cf * 16 + ccol;
                #pragma unroll
                for (int ii = 0; ii < 4; ++ii)
                    T[(rf2 * 16 + crow + ii) * 260 + col] = acc[rf][cf][ii];
            }
        }
        __syncthreads();
        #pragma unroll
        for (int p = 0; p < 4; ++p) {  // 2048 float4 items: [32][64]
            int flat = tid + p * 512;
            int r = flat >> 6, jc = flat & 63;
            int gm = m0 + half * 32 + r;
            if (gm < N_NODES) {
                f32x4 v = *(f32x4*)&T[r * 260 + jc * 4];
                f32x4 bb = *(const f32x4*)&bf[jc * 4];
                f32x4 o;
                #pragma unroll
                for (int q = 0; q < 4; ++q) o[q] = fmaxf(v[q] + bb[q], 0.f);
                *(f32x4*)&out[(size_t)gm * H_F + jc * 4] = o;
            }
        }
    }
}

extern "C" void kernel_launch(void* const* d_in, const int* in_sizes, int n_in,
                              void* d_out, int out_size, void* d_ws, size_t ws_size,
                              hipStream_t stream) {
    const int* ei = (const int*)d_in[0];
    const int* rows = ei;
    const int* cols = ei + N_EDGES;
    const float* feat = (const float*)d_in[1];
    const float* Ws = (const float*)d_in[2];
    const float* bs = (const float*)d_in[3];
    const float* Wf = (const float*)d_in[4];
    const float* bf = (const float*)d_in[5];
    float* out = (float*)d_out;

    // workspace layout (~52 MB)
    ushort* h0 = (ushort*)d_ws;                    // 4 x 4,800,000 u16 (bf16 h chain)
    ushort* h1 = h0 + (size_t)N_NODES * IN_F;
    ushort* h2 = h1 + (size_t)N_NODES * IN_F;
    ushort* h3 = h2 + (size_t)N_NODES * IN_F;
    ushort* Ws2 = h3 + (size_t)N_NODES * IN_F;     // 98,304 u16 (frag-major)
    ushort* Wf2 = Ws2 + N_NIE * IN_F * H_F;        // 262,144 u16 (frag-major)
    float* dinv = (float*)(Wf2 + N_NIE * H_F * H_F);  // 50,000 f32
    int* rowptr = (int*)(dinv + N_NODES);          // 50,004 i32
    int* bsum = rowptr + 50004;                    // 256 i32
    int* boff = bsum + 256;                        // 256 i32 (pads cw to 8B alignment)
    int2* cw = (int2*)(boff + 256);                // 800,000 int2 (col, dinv)
    // CSR-build temporaries aliased into h1 (h1 written only later, by spmm)
    int* cnt = (int*)h1;
    int* cursor = cnt + N_NODES;

    hipMemsetAsync(cnt, 0, N_NODES * sizeof(int), stream);
    k_count_prep<<<CP_COUNT_NB + PREP_NORM_NB + PREP_WS_NB + PREP_WF_NB, 256, 0, stream>>>(
        rows, cols, cnt, feat, h0, Ws, Ws2, Wf, Wf2);
    k_scan1<<<SCAN_NB, 256, 0, stream>>>(cnt, rowptr, bsum);
    k_scan2<<<1, 256, 0, stream>>>(bsum, boff, rowptr);
    k_scan3<<<SCAN_NB, 256, 0, stream>>>(boff, cnt, rowptr, cursor, dinv);
    k_scatter<<<(N_EDGES + 255) / 256, 256, 0, stream>>>(rows, cols, dinv, cursor, cw);

    // hop chain first (h1..h3), then one fused GEMM pass
    k_spmm_csr<<<(N_NODES * 16 + 255) / 256, 256, 0, stream>>>(rowptr, cw, dinv, h0, h1);
    k_spmm_csr<<<(N_NODES * 16 + 255) / 256, 256, 0, stream>>>(rowptr, cw, dinv, h1, h2);
    k_spmm_csr<<<(N_NODES * 16 + 255) / 256, 256, 0, stream>>>(rowptr, cw, dinv, h2, h3);
    k_mega<<<NBLK, 512, 0, stream>>>(h0, h1, h2, h3, Ws2, bs, Wf2, bf, out);
}

// Round 26
// 286.130 us; speedup vs baseline: 1.0130x; 1.0130x over previous
//
#include <hip/hip_runtime.h>

#define N_NODES 50000
#define N_EDGES 800000
#define IN_F 96
#define H_F 256
#define N_NIE 4
#define SCAN_NB 196   // ceil(50000/256)
#define BM 64         // mega rows per block
#define NBLK 782      // ceil(50000/64)
#define LDA1 104      // A-lds stride (shorts): 208B rows
// merged count+prep kernel grid partition
#define CP_COUNT_NB 1563                   // ceil(400000/256) int2 edge pairs
#define PREP_NORM_NB 12500                 // 4 nodes/block (wave per node)
#define PREP_WS_NB 384                     // ceil(4*96*256/256)
#define PREP_WF_NB 1024                    // ceil(4*256*256/256)

typedef float f32x4 __attribute__((ext_vector_type(4)));
typedef short s16x8 __attribute__((ext_vector_type(8)));
typedef unsigned short ushort;

__device__ __forceinline__ ushort bf16_rne(float f) {
    unsigned u = __float_as_uint(f);
    u += 0x7fffu + ((u >> 16) & 1u);
    return (ushort)(u >> 16);
}
__device__ __forceinline__ float bf16_f(ushort h) {
    return __uint_as_float(((unsigned)h) << 16);
}

// ---------------- merged: edge-degree count + row-normalize + weight re-layouts ----------------
__global__ __launch_bounds__(256) void k_count_prep(const int* __restrict__ rows,
                                                    const int* __restrict__ cols,
                                                    int* __restrict__ cnt,
                                                    const float* __restrict__ feat,
                                                    ushort* __restrict__ x,
                                                    const float* __restrict__ Ws,
                                                    ushort* __restrict__ Ws2,
                                                    const float* __restrict__ Wf,
                                                    ushort* __restrict__ Wf2) {
    int blk = blockIdx.x;
    if (blk < CP_COUNT_NB) {
        int i = blk * 256 + threadIdx.x;
        if (i >= N_EDGES / 2) return;
        int2 r2 = ((const int2*)rows)[i];
        int2 c2 = ((const int2*)cols)[i];
        if (r2.x != c2.x) atomicAdd(&cnt[r2.x], 1);
        if (r2.y != c2.y) atomicAdd(&cnt[r2.y], 1);
    } else if (blk < CP_COUNT_NB + PREP_NORM_NB) {
        int wid = ((blk - CP_COUNT_NB) * 256 + threadIdx.x) >> 6;
        int lane = threadIdx.x & 63;
        if (wid >= N_NODES) return;
        const float* fr = feat + (size_t)wid * IN_F;
        float v0 = (lane < IN_F) ? fr[lane] : 0.0f;
        float v1 = (lane < IN_F - 64) ? fr[64 + lane] : 0.0f;
        float ss = v0 * v0 + v1 * v1;
        #pragma unroll
        for (int o = 32; o; o >>= 1) ss += __shfl_xor(ss, o, 64);
        float inv = 1.0f / fmaxf(sqrtf(ss), 1e-12f);
        ushort* xr = x + (size_t)wid * IN_F;
        if (lane < IN_F) xr[lane] = bf16_rne(v0 * inv);
        if (lane < IN_F - 64) xr[64 + lane] = bf16_rne(v1 * inv);
    } else if (blk < CP_COUNT_NB + PREP_NORM_NB + PREP_WS_NB) {
        int idx = (blk - CP_COUNT_NB - PREP_NORM_NB) * 256 + threadIdx.x;
        if (idx >= N_NIE * IN_F * H_F) return;
        int hop = idx / (IN_F * H_F), rem = idx % (IN_F * H_F);
        int k = rem / H_F, n = rem % H_F;
        int c = n >> 6, wc = (n >> 5) & 1, b = (n >> 4) & 1, rsel = n & 15;
        int ks = k >> 5, kk = k & 31;
        int lane = (kk >> 3) * 16 + rsel, sel8 = kk & 7;
        int d = (((((hop * 4 + c) * 2 + wc) * 2 + b) * 3 + ks) * 64 + lane) * 8 + sel8;
        Ws2[d] = bf16_rne(Ws[idx]);
    } else {
        int idx = (blk - CP_COUNT_NB - PREP_NORM_NB - PREP_WS_NB) * 256 + threadIdx.x;
        if (idx >= N_NIE * H_F * H_F) return;
        int hop = idx / (H_F * H_F), rem = idx % (H_F * H_F);
        int k = rem / H_F, n = rem % H_F;
        int kc = k >> 5, kk = k & 31;
        int w = n >> 5, rem2 = n & 31;
        int cf = rem2 >> 4, rsel = rem2 & 15;
        int lane = (kk >> 3) * 16 + rsel, sel8 = kk & 7;
        int d = ((((hop * 8 + kc) * 8 + w) * 2 + cf) * 64 + lane) * 8 + sel8;
        Wf2[d] = bf16_rne(Wf[idx]);
    }
}

__global__ __launch_bounds__(256) void k_scan1(const int* __restrict__ cnt,
                                               int* __restrict__ rowptr,
                                               int* __restrict__ bsum) {
    __shared__ int s[256];
    int t = threadIdx.x, e = blockIdx.x * 256 + t;
    int v = (e < N_NODES) ? cnt[e] : 0;
    s[t] = v;
    __syncthreads();
    #pragma unroll
    for (int off = 1; off < 256; off <<= 1) {
        int nv = (t >= off) ? s[t - off] : 0;
        __syncthreads();
        s[t] += nv;
        __syncthreads();
    }
    if (e < N_NODES) rowptr[e] = s[t] - v;
    if (t == 255) bsum[blockIdx.x] = s[255];
}

__global__ __launch_bounds__(256) void k_scan2(int* __restrict__ bsum,
                                               int* __restrict__ boff,
                                               int* __restrict__ rowptr) {
    __shared__ int s[256];
    int t = threadIdx.x;
    int v = (t < SCAN_NB) ? bsum[t] : 0;
    s[t] = v;
    __syncthreads();
    #pragma unroll
    for (int off = 1; off < 256; off <<= 1) {
        int nv = (t >= off) ? s[t - off] : 0;
        __syncthreads();
        s[t] += nv;
        __syncthreads();
    }
    if (t < SCAN_NB) boff[t] = s[t] - v;
    if (t == 255) rowptr[N_NODES] = s[255];
}

__global__ __launch_bounds__(256) void k_scan3(const int* __restrict__ boff,
                                               const int* __restrict__ cnt,
                                               int* __restrict__ rowptr,
                                               int* __restrict__ cursor,
                                               float* __restrict__ dinv) {
    int e = blockIdx.x * 256 + threadIdx.x;
    if (e >= N_NODES) return;
    int r = rowptr[e] + boff[blockIdx.x];
    rowptr[e] = r;
    cursor[e] = r;
    dinv[e] = rsqrtf((float)cnt[e] + 1.0f);
}

// single-pass scatter; packs (col, dinv[col])
__global__ __launch_bounds__(256) void k_scatter(const int* __restrict__ rows,
                                                 const int* __restrict__ cols,
                                                 const float* __restrict__ dinv,
                                                 int* __restrict__ cursor,
                                                 int2* __restrict__ cw) {
    int e = blockIdx.x * 256 + threadIdx.x;
    if (e >= N_EDGES) return;
    int r = rows[e], c = cols[e];
    if (r == c) return;  // set_diag zeroes pre-existing diagonal entries
    int p = atomicAdd(&cursor[r], 1);
    long long v = ((long long)(unsigned)__float_as_int(dinv[c]) << 32) | (unsigned)c;
    __builtin_nontemporal_store(v, (long long*)&cw[p]);
}

// ---------------- CSR SpMM: 16-lane group/row, packed (c,w) int2, s16x8 gathers, unroll 4 ----
__global__ __launch_bounds__(256) void k_spmm_csr(const int* __restrict__ rowptr,
                                                  const int2* __restrict__ cw,
                                                  const float* __restrict__ dinv,
                                                  const ushort* __restrict__ x,
                                                  ushort* __restrict__ y) {
    int g = (blockIdx.x * 256 + threadIdx.x) >> 4;
    if (g >= N_NODES) return;
    int l = threadIdx.x & 15;
    bool act = l < 12;
    float dr = dinv[g];
    s16x8 sv = {0, 0, 0, 0, 0, 0, 0, 0};
    if (act) sv = *(const s16x8*)&x[(size_t)g * IN_F + l * 8];
    float a[8] = {}, b[8] = {};
    int k = rowptr[g], e = rowptr[g + 1];
    for (; k + 3 < e; k += 4) {  // 4 gather chains in flight; weight rides with index
        int2 p0 = cw[k], p1 = cw[k + 1], p2 = cw[k + 2], p3 = cw[k + 3];
        float w0 = __int_as_float(p0.y), w1 = __int_as_float(p1.y);
        float w2 = __int_as_float(p2.y), w3 = __int_as_float(p3.y);
        s16x8 v0 = {0, 0, 0, 0, 0, 0, 0, 0}, v1 = v0, v2 = v0, v3 = v0;
        if (act) {
            v0 = *(const s16x8*)&x[(size_t)p0.x * IN_F + l * 8];
            v1 = *(const s16x8*)&x[(size_t)p1.x * IN_F + l * 8];
            v2 = *(const s16x8*)&x[(size_t)p2.x * IN_F + l * 8];
            v3 = *(const s16x8*)&x[(size_t)p3.x * IN_F + l * 8];
        }
        #pragma unroll
        for (int q = 0; q < 8; ++q) {
            a[q] += bf16_f((ushort)v0[q]) * w0 + bf16_f((ushort)v1[q]) * w1;
            b[q] += bf16_f((ushort)v2[q]) * w2 + bf16_f((ushort)v3[q]) * w3;
        }
    }
    for (; k < e; ++k) {
        int2 p0 = cw[k];
        float w0 = __int_as_float(p0.y);
        s16x8 v0 = {0, 0, 0, 0, 0, 0, 0, 0};
        if (act) v0 = *(const s16x8*)&x[(size_t)p0.x * IN_F + l * 8];
        #pragma unroll
        for (int q = 0; q < 8; ++q) a[q] += bf16_f((ushort)v0[q]) * w0;
    }
    if (act) {
        s16x8 o;
        #pragma unroll
        for (int q = 0; q < 8; ++q)
            o[q] = (short)bf16_rne(dr * ((a[q] + b[q]) + dr * bf16_f((ushort)sv[q])));
        *(s16x8*)&y[(size_t)g * IN_F + l * 8] = o;
    }
}

// ---------------- MEGA v10 (proven 102 us): frag-major weights, A-prefetch ----------------
// LDS: Ah (13.3 KB) + nsH (32 KB) = 45.3 KB. No setprio. No spill (cap 128 VGPR).
// out = relu( sum_i relu(h_i @ WsT_i + bs_i) @ WfT_i + bf ), written once.
__global__ __launch_bounds__(512, 4) void k_mega(const ushort* __restrict__ h0,
                                                 const ushort* __restrict__ h1,
                                                 const ushort* __restrict__ h2,
                                                 const ushort* __restrict__ h3,
                                                 const ushort* __restrict__ Ws2,
                                                 const float* __restrict__ bs,
                                                 const ushort* __restrict__ Wf2,
                                                 const float* __restrict__ bf,
                                                 float* __restrict__ out) {
    __shared__ ushort SM[23040];        // 46.1 KB
    ushort* nsH = SM;                   // [64][256] swizzled (16384)
    ushort* Ah  = SM + 16384;           // [64][LDA1] (6656)
    float* T = (float*)SM;              // epilogue scratch [32][260] f32 (aliases)

    int m0 = blockIdx.x * BM;
    int tid = threadIdx.x;
    int lane = tid & 63, w = tid >> 6;
    int rsel = lane & 15, g = lane >> 4, ksel = g * 8;
    int crow = g * 4, ccol = rsel;
    int rw0 = (w & 3) * 16;   // phase-1 row-fragment base
    int wc = w >> 2;          // phase-1 col-half (0/1)
    int cwb = wc * 32;

    int sr0 = tid / 12, sj0 = tid - sr0 * 12;  // A-stage item 0 of [64][12]
    int f1 = tid + 512;
    int sr1 = f1 / 12, sj1 = f1 - sr1 * 12;    // A-stage item 1 (tid < 256)
    int gm0 = m0 + sr0, gm1 = m0 + sr1;

    f32x4 acc[4][2] = {};  // persistent: rows rf*16.., cols w*32+cf*16..

    // ---- prologue: stage h0 into Ah ----
    {
        s16x8 v = {0, 0, 0, 0, 0, 0, 0, 0};
        if (gm0 < N_NODES) v = *(const s16x8*)&h0[(size_t)gm0 * IN_F + sj0 * 8];
        *(s16x8*)&Ah[sr0 * LDA1 + sj0 * 8] = v;
        if (tid < 256) {
            s16x8 v1 = {0, 0, 0, 0, 0, 0, 0, 0};
            if (gm1 < N_NODES) v1 = *(const s16x8*)&h0[(size_t)gm1 * IN_F + sj1 * 8];
            *(s16x8*)&Ah[sr1 * LDA1 + sj1 * 8] = v1;
        }
    }
    __syncthreads();

    for (int hop = 0; hop < N_NIE; ++hop) {
        const ushort* wsF = Ws2 + (size_t)hop * IN_F * H_F;  // frag-major
        const ushort* wfF = Wf2 + (size_t)hop * H_F * H_F;   // frag-major
        const float* bsi = bs + hop * H_F;

        // ---- phase 1: nsH = relu(A @ WsT + bs); B frags direct global ----
        #pragma unroll
        for (int c = 0; c < 4; ++c) {
            const ushort* bsrc = wsF + (size_t)((c * 2 + wc) * 2) * 3 * 64 * 8;  // b=0 base
            f32x4 ac[2] = {};
            #pragma unroll
            for (int ks = 0; ks < 3; ++ks) {
                s16x8 ah = *(const s16x8*)&Ah[(rw0 + rsel) * LDA1 + ks * 32 + ksel];
                s16x8 b0 = *(const s16x8*)&bsrc[(size_t)(ks * 64 + lane) * 8];
                s16x8 b1 = *(const s16x8*)&bsrc[(size_t)((3 + ks) * 64 + lane) * 8];
                ac[0] = __builtin_amdgcn_mfma_f32_16x16x32_bf16(ah, b0, ac[0], 0, 0, 0);
                ac[1] = __builtin_amdgcn_mfma_f32_16x16x32_bf16(ah, b1, ac[1], 0, 0, 0);
            }
            #pragma unroll
            for (int cf = 0; cf < 2; ++cf) {
                int col = c * 64 + cwb + cf * 16 + ccol;
                float bb = bsi[col];
                #pragma unroll
                for (int ii = 0; ii < 4; ++ii) {
                    int row = rw0 + crow + ii;
                    nsH[row * 256 + (col ^ ((row & 7) << 3))] =
                        bf16_rne(fmaxf(ac[cf][ii] + bb, 0.f));
                }
            }
        }
        __syncthreads();  // nsH complete; Ah reads drained -> Ah writable
        // ---- issue next-hop A loads (hidden under phase 2), write to Ah ----
        if (hop < N_NIE - 1) {
            const ushort* An = (hop == 0) ? h1 : (hop == 1) ? h2 : h3;
            s16x8 pv0 = {0, 0, 0, 0, 0, 0, 0, 0}, pv1 = pv0;
            if (gm0 < N_NODES) pv0 = *(const s16x8*)&An[(size_t)gm0 * IN_F + sj0 * 8];
            if (tid < 256 && gm1 < N_NODES) pv1 = *(const s16x8*)&An[(size_t)gm1 * IN_F + sj1 * 8];
            *(s16x8*)&Ah[sr0 * LDA1 + sj0 * 8] = pv0;
            if (tid < 256) *(s16x8*)&Ah[sr1 * LDA1 + sj1 * 8] = pv1;
        }
        // ---- phase 2: acc += ns @ WfT; W frags direct global ----
        #pragma unroll
        for (int kc = 0; kc < 8; ++kc) {
            int k0 = kc * 32 + ksel;
            s16x8 ah4[4];
            #pragma unroll
            for (int rf = 0; rf < 4; ++rf) {
                int row = rf * 16 + rsel;
                ah4[rf] = *(const s16x8*)&nsH[row * 256 + (k0 ^ ((row & 7) << 3))];
            }
            #pragma unroll
            for (int cf = 0; cf < 2; ++cf) {
                s16x8 bh = *(const s16x8*)&wfF[(size_t)(((kc * 8 + w) * 2 + cf) * 64 + lane) * 8];
                #pragma unroll
                for (int rf = 0; rf < 4; ++rf)
                    acc[rf][cf] = __builtin_amdgcn_mfma_f32_16x16x32_bf16(ah4[rf], bh, acc[rf][cf], 0, 0, 0);
            }
        }
        __syncthreads();  // nsH consumed + Ah(next) published
    }
    // ---- epilogue: transpose acc through LDS -> full-line float4 row stores ----
    #pragma unroll
    for (int half = 0; half < 2; ++half) {
        __syncthreads();  // prior T / LDS reads done
        #pragma unroll
        for (int rf2 = 0; rf2 < 2; ++rf2) {
            int rf = half * 2 + rf2;
            #pragma unroll
            for (int cf = 0; cf < 2; ++cf) {
                int col = w * 32 + cf * 16 + ccol;
                #pragma unroll
                for (int ii = 0; ii < 4; ++ii)
                    T[(rf2 * 16 + crow + ii) * 260 + col] = acc[rf][cf][ii];
            }
        }
        __syncthreads();
        #pragma unroll
        for (int p = 0; p < 4; ++p) {  // 2048 float4 items: [32][64]
            int flat = tid + p * 512;
            int r = flat >> 6, jc = flat & 63;
            int gm = m0 + half * 32 + r;
            if (gm < N_NODES) {
                f32x4 v = *(f32x4*)&T[r * 260 + jc * 4];
                f32x4 bb = *(const f32x4*)&bf[jc * 4];
                f32x4 o;
                #pragma unroll
                for (int q = 0; q < 4; ++q) o[q] = fmaxf(v[q] + bb[q], 0.f);
                *(f32x4*)&out[(size_t)gm * H_F + jc * 4] = o;
            }
        }
    }
}

extern "C" void kernel_launch(void* const* d_in, const int* in_sizes, int n_in,
                              void* d_out, int out_size, void* d_ws, size_t ws_size,
                              hipStream_t stream) {
    const int* ei = (const int*)d_in[0];
    const int* rows = ei;
    const int* cols = ei + N_EDGES;
    const float* feat = (const float*)d_in[1];
    const float* Ws = (const float*)d_in[2];
    const float* bs = (const float*)d_in[3];
    const float* Wf = (const float*)d_in[4];
    const float* bf = (const float*)d_in[5];
    float* out = (float*)d_out;

    // workspace layout (~52 MB)
    ushort* h0 = (ushort*)d_ws;                    // 4 x 4,800,000 u16 (bf16 h chain)
    ushort* h1 = h0 + (size_t)N_NODES * IN_F;
    ushort* h2 = h1 + (size_t)N_NODES * IN_F;
    ushort* h3 = h2 + (size_t)N_NODES * IN_F;
    ushort* Ws2 = h3 + (size_t)N_NODES * IN_F;     // 98,304 u16 (frag-major)
    ushort* Wf2 = Ws2 + N_NIE * IN_F * H_F;        // 262,144 u16 (frag-major)
    float* dinv = (float*)(Wf2 + N_NIE * H_F * H_F);  // 50,000 f32
    int* rowptr = (int*)(dinv + N_NODES);          // 50,004 i32
    int* bsum = rowptr + 50004;                    // 256 i32
    int* boff = bsum + 256;                        // 256 i32 (pads cw to 8B alignment)
    int2* cw = (int2*)(boff + 256);                // 800,000 int2 (col, dinv)
    // CSR-build temporaries aliased into h1 (h1 written only later, by spmm)
    int* cnt = (int*)h1;
    int* cursor = cnt + N_NODES;

    hipMemsetAsync(cnt, 0, N_NODES * sizeof(int), stream);
    k_count_prep<<<CP_COUNT_NB + PREP_NORM_NB + PREP_WS_NB + PREP_WF_NB, 256, 0, stream>>>(
        rows, cols, cnt, feat, h0, Ws, Ws2, Wf, Wf2);
    k_scan1<<<SCAN_NB, 256, 0, stream>>>(cnt, rowptr, bsum);
    k_scan2<<<1, 256, 0, stream>>>(bsum, boff, rowptr);
    k_scan3<<<SCAN_NB, 256, 0, stream>>>(boff, cnt, rowptr, cursor, dinv);
    k_scatter<<<(N_EDGES + 255) / 256, 256, 0, stream>>>(rows, cols, dinv, cursor, cw);

    // hop chain first (h1..h3), then one fused GEMM pass
    k_spmm_csr<<<(N_NODES * 16 + 255) / 256, 256, 0, stream>>>(rowptr, cw, dinv, h0, h1);
    k_spmm_csr<<<(N_NODES * 16 + 255) / 256, 256, 0, stream>>>(rowptr, cw, dinv, h1, h2);
    k_spmm_csr<<<(N_NODES * 16 + 255) / 256, 256, 0, stream>>>(rowptr, cw, dinv, h2, h3);
    k_mega<<<NBLK, 512, 0, stream>>>(h0, h1, h2, h3, Ws2, bs, Wf2, bf, out);
}